// Round 10
// baseline (2182.844 us; speedup 1.0000x reference)
//
#include <hip/hip_runtime.h>
#include <hip/hip_bf16.h>

// Problem constants
#define Bn 256
#define Tn 336
#define KE 16

typedef __attribute__((ext_vector_type(8))) __bf16 bf16x8;
typedef __attribute__((ext_vector_type(4))) float f32x4;
typedef unsigned long long u64t;
typedef unsigned int u32t;

#define MFMA(a, b, c) __builtin_amdgcn_mfma_f32_16x16x32_bf16((a), (b), (c), 0, 0, 0)
#define BC8(x) __builtin_bit_cast(bf16x8, (x))
#define VDRAIN() asm volatile("s_waitcnt vmcnt(0)" ::: "memory")

// ---------------- pack kernels (once per launch) ----------------

__global__ void pack_wh(const float* __restrict__ Wh, __bf16* __restrict__ hi,
                        __bf16* __restrict__ lo) {
    int i = blockIdx.x * 256 + threadIdx.x;  // 512*256
    int k = i >> 8, n = i & 255;
    float v = Wh[i];
    __bf16 h = (__bf16)v;
    hi[n * 512 + k] = h;
    lo[n * 512 + k] = (__bf16)(v - (float)h);
}

__global__ void pack_wx(const float* __restrict__ Wx, __bf16* __restrict__ out) {
    int i = blockIdx.x * 256 + threadIdx.x;  // 256*32
    int n = i >> 5, k = i & 31;
    out[i] = (__bf16)((k < 17) ? Wx[k * 256 + n] : 0.f);
}

__global__ void pack_split(const float* __restrict__ in, __bf16* __restrict__ hi,
                           __bf16* __restrict__ lo, int n) {
    int i = blockIdx.x * 256 + threadIdx.x;
    if (i >= n) return;
    float v = in[i];
    __bf16 h = (__bf16)v;
    hi[i] = h;
    lo[i] = (__bf16)(v - (float)h);
}

__global__ void pack_xin(const float* __restrict__ xl, const float* __restrict__ xe,
                         __bf16* __restrict__ out) {
    int i = blockIdx.x * 256 + threadIdx.x;  // 336*256*32
    int k = i & 31, b = (i >> 5) & 255, t = i >> 13;
    float v = 0.f;
    if (k == 0) v = xl[b * Tn + t];
    else if (k < 17) v = xe[(b * Tn + t) * KE + (k - 1)];
    out[i] = (__bf16)v;
}

// ---------------- MALL-coherent helpers (relaxed agent = sc1) ----------------

__device__ __forceinline__ u32t ald32(const u32t* p) {
    return __hip_atomic_load(p, __ATOMIC_RELAXED, __HIP_MEMORY_SCOPE_AGENT);
}
__device__ __forceinline__ void ast32(u32t* p, u32t v) {
    __hip_atomic_store(p, v, __ATOMIC_RELAXED, __HIP_MEMORY_SCOPE_AGENT);
}
__device__ __forceinline__ bf16x8 ld16_mall(const __bf16* p) {
    union { u64t q[2]; bf16x8 v; } r;
    const u64t* q = (const u64t*)p;
    r.q[0] = __hip_atomic_load(q, __ATOMIC_RELAXED, __HIP_MEMORY_SCOPE_AGENT);
    r.q[1] = __hip_atomic_load(q + 1, __ATOMIC_RELAXED, __HIP_MEMORY_SCOPE_AGENT);
    return r.v;
}
__device__ __forceinline__ void st16_mall(__bf16* p, f32x4 v) {
    union { f32x4 f; u64t q[2]; } u; u.f = v;
    __hip_atomic_store((u64t*)p, u.q[0], __ATOMIC_RELAXED, __HIP_MEMORY_SCOPE_AGENT);
    __hip_atomic_store((u64t*)p + 1, u.q[1], __ATOMIC_RELAXED, __HIP_MEMORY_SCOPE_AGENT);
}

// ---------------- persistent GRU kernel, 2-cohort pipelined ----------------
// grid = 256 blocks (1/CU), block = 512 threads (8 waves). group g = bid&7
// (32 blocks); block l = bid>>3 owns hidden units [16l,16l+16).
// Batch rows of group split into cohort A (rows 0-15) / B (rows 16-31) —
// independent recurrences; per step: phA(A) phA(B) phB(A) phB(B), each
// flag's MALL latency hidden by the other cohort's slot.
// Waves 0..5: gh (gate=w>>1, K-half=w&1). Wave 6: full-K x' tile for
// cohort myc=l&1, cols [16*(l>>1),+16). Wave 7: staging only.
// h double-buffered by step parity (overwrite-safety via flag transitivity).

__global__ __launch_bounds__(512, 2)
__attribute__((amdgpu_waves_per_eu(2, 2)))
void gru_persist(
    const __bf16* __restrict__ WhT_hi, const __bf16* __restrict__ WhT_lo,
    const __bf16* __restrict__ WxTP,
    const __bf16* __restrict__ Wih_hi, const __bf16* __restrict__ Wih_lo,
    const __bf16* __restrict__ Whh_hi, const __bf16* __restrict__ Whh_lo,
    const __bf16* __restrict__ XinP,
    const float* __restrict__ b_t, const float* __restrict__ b_ih,
    const float* __restrict__ b_hh,
    __bf16* xp, __bf16* hbf,  // MALL-shared (sc1)
    u32t* cnt, float* __restrict__ out)
{
    __shared__ __align__(16) char lds[92672];
    // [0,16384):      hT   16 rows x 1024B (bf16 k=512), XOR-swizzled
    // [16384,24576):  xT   16 rows x 512B  (bf16 k=256), XOR-swizzled
    // [24576,36864):  exG  [coh][3 gate][2 kh][256] f32 (gh partials)
    // [36864,43008):  exX  [3 gate][2 kh][256] f32 (gx partials)
    // [43008,43520):  pk   512B pack buffer (x' tile / h tile)
    // [43520,92672):  wB   W_ih slice: hi 48x512B | lo 48x512B, swizzled

    char* hT = lds;
    char* xT = lds + 16384;
    float* exG = (float*)(lds + 24576);
    float* exX = (float*)(lds + 36864);
    char* pk = lds + 43008;
    char* wB = lds + 43520;

    const int bid = blockIdx.x;
    const int g = bid & 7, l = bid >> 3;
    const int tid = threadIdx.x;
    const int w = tid >> 6, lane = tid & 63;
    const int lr = lane & 15, ko = (lane >> 4) << 3;
    const int gg = w >> 1, kh = w & 1;
    const int cb = l >> 1, myc = l & 1;

    __bf16* xp_g = xp + g * (2 * 16 * 256);     // [coh][16][256]
    const int HBP = 8 * 32 * 512;               // h parity stride (elems)
    __bf16* hb_g = hbf + g * (32 * 512);        // + parity*HBP
    u32t* fl = cnt + g * 128;  // lines: [0,32)=x'A [32,64)=x'B [64,96)=hA [96,128)=hB

    // ---- stage W_ih slice -> wB LDS (once; reused 336 steps) ----
#pragma unroll
    for (int e = 0; e < 3; ++e) {
        int idx = e * 512 + tid;            // 1536 chunks: 48 rows x 32 segs
        int row = idx >> 5, seg = idx & 31;
        int gate = row >> 4, r = row & 15;
        size_t src = (size_t)(gate * 512 + l * 16 + r) * 256 + seg * 8;
        int dst = (row * 512 + seg * 16) ^ ((row & 7) << 4);
        *(bf16x8*)(wB + dst)         = *(const bf16x8*)(Wih_hi + src);
        *(bf16x8*)(wB + 24576 + dst) = *(const bf16x8*)(Wih_lo + src);
    }

    // ---- phase-A weights (waves 0-5: Whh (gate,kh)-slice in [0,8);
    //      wave 6: full-K Wh col-slice in [0,16); wave 7: dummy) ----
    const __bf16 *sH0, *sL0, *sH1, *sL1;
    if (w < 6) {
        size_t j = (size_t)(gg * 512 + l * 16 + lr) * 512 + kh * 256 + ko;
        sH0 = Whh_hi + j; sL0 = Whh_lo + j; sH1 = sH0; sL1 = sL0;
    } else {
        size_t j = (size_t)(cb * 16 + lr) * 512 + ko;
        sH0 = WhT_hi + j; sL0 = WhT_lo + j; sH1 = sH0 + 256; sL1 = sL0 + 256;
    }
    f32x4 wHi[16], wLo[16];
#pragma unroll
    for (int k0 = 0; k0 < 8; ++k0) {
        wHi[k0]     = *(const f32x4*)(sH0 + k0 * 32);
        wLo[k0]     = *(const f32x4*)(sL0 + k0 * 32);
        wHi[8 + k0] = *(const f32x4*)(sH1 + k0 * 32);
        wLo[8 + k0] = *(const f32x4*)(sL1 + k0 * 32);
    }
    bf16x8 wxf = {};
    float bt_r = 0.f;
    if (w == 6) {
        wxf = *(const bf16x8*)(WxTP + (size_t)(cb * 16 + lr) * 32 + ko);
        bt_r = b_t[cb * 16 + lr];
    }

    // elementwise per-thread state: (row = tid>>4 in group, unit = tid&15)
    const int erow = tid >> 4, eunit = tid & 15;
    const int ecoh = erow >> 4, er = erow & 15;
    float bi0, bi1, bi2, bh0, bh1, bh2;
    {
        int u = l * 16 + eunit;
        bi0 = b_ih[u]; bi1 = b_ih[512 + u]; bi2 = b_ih[1024 + u];
        bh0 = b_hh[u]; bh1 = b_hh[512 + u]; bh2 = b_hh[1024 + u];
    }
    float hreg = 0.f;  // fp32 h carried in-register across all steps

    __syncthreads();   // wB staged before any use

    for (int t = 0; t < Tn; ++t) {
        const int hprev = (t & 1) ^ 1, hcur = t & 1;
        const u32t tg = (u32t)(t + 1);

        // pin phase-A weights as loop-carried opaque register values
#pragma unroll
        for (int k0 = 0; k0 < 16; ++k0)
            asm volatile("" : "+v"(wHi[k0]), "+v"(wLo[k0]));

        // ================= phA for cohorts 0,1 =================
        for (int c = 0; c < 2; ++c) {
            // wait h_c[t-1] flags (all 32 blocks)
            if (w == 0) {
                const u32t* fp = fl + 64 + c * 32 + (lane & 31);
                for (;;) {
                    u32t v = ald32(fp);
                    if (__all((int)(v >= (u32t)t))) break;
                    __builtin_amdgcn_s_sleep(1);
                }
            }
            __syncthreads();
            // stage h_c -> hT (1024 x 16B chunks, 2/thread)
            {
                const __bf16* hsrc = hb_g + hprev * HBP + c * (16 * 512);
#pragma unroll
                for (int e = 0; e < 2; ++e) {
                    int idx = e * 512 + tid;
                    int row = idx >> 6, seg = idx & 63;
                    bf16x8 v = ld16_mall(hsrc + row * 512 + seg * 8);
                    *(bf16x8*)(hT + ((row * 1024 + seg * 16) ^ ((row & 7) << 4))) = v;
                }
            }
            __syncthreads();
            // gh: waves 0-5 (gate, K-half), 16 MFMA each
            if (w < 6) {
                f32x4 aH = {}, aL = {};
#pragma unroll
                for (int k0 = 0; k0 < 8; ++k0) {
                    bf16x8 a = *(const bf16x8*)(hT +
                        ((lr * 1024 + kh * 512 + (lane >> 4) * 16 + k0 * 64) ^
                         ((lr & 7) << 4)));
                    aH = MFMA(a, BC8(wHi[k0]), aH);
                    aL = MFMA(a, BC8(wLo[k0]), aL);
                }
                f32x4 acc = aH + aL;
                float* dst = exG + ((c * 3 + gg) * 2 + kh) * 256;
#pragma unroll
                for (int r = 0; r < 4; ++r)
                    dst[((lane >> 4) * 4 + r) * 16 + lr] = acc[r];
            } else if (w == 6 && myc == c) {
                // full-K 16x16 x' tile (33 MFMA) + pack + MALL store + flag
                f32x4 aH = {}, aL = {};
#pragma unroll
                for (int q = 0; q < 16; ++q) {
                    int k6 = q >> 3, k0 = q & 7;
                    bf16x8 a = *(const bf16x8*)(hT +
                        ((lr * 1024 + k6 * 512 + (lane >> 4) * 16 + k0 * 64) ^
                         ((lr & 7) << 4)));
                    aH = MFMA(a, BC8(wHi[q]), aH);
                    aL = MFMA(a, BC8(wLo[q]), aL);
                }
                bf16x8 ax = *(const bf16x8*)(XinP +
                    ((size_t)t * 256 + g * 32 + c * 16 + lr) * 32 + ko);
                aH = MFMA(ax, wxf, aH);
                f32x4 acc = aH + aL;
#pragma unroll
                for (int r = 0; r < 4; ++r) {
                    int row = (lane >> 4) * 4 + r;
                    float e2 = __expf(2.f * (acc[r] + bt_r));
                    float tv = 1.f - 2.f / (e2 + 1.f);
                    *(__bf16*)(pk + (row * 16 + lr) * 2) = (__bf16)tv;
                }
                // lanes 0-31: 16B chunk stores (within-wave lgkm ordering)
                if (lane < 32) {
                    f32x4 pv = *(const f32x4*)(pk + lane * 16);
                    st16_mall(xp_g + c * 4096 + (lane >> 1) * 256 + cb * 16 +
                              (lane & 1) * 8, pv);
                }
                VDRAIN();  // wave-local drain, then post x' flag
                if (lane == 0) ast32(fl + c * 32 + cb, tg);
            }
            // no block sync here: next slot's poll-sync orders hT reuse
        }

        // ================= phB for cohorts 0,1 =================
        for (int c = 0; c < 2; ++c) {
            // wait x'_c flags (16 producer blocks)
            if (w == 0) {
                const u32t* fp = fl + c * 32 + (lane & 15);
                for (;;) {
                    u32t v = ald32(fp);
                    if (__all((int)(v >= tg))) break;
                    __builtin_amdgcn_s_sleep(1);
                }
            }
            __syncthreads();
            // stage x'_c -> xT (512 x 16B chunks, 1/thread)
            {
                int row = tid >> 5, seg = tid & 31;
                bf16x8 v = ld16_mall(xp_g + c * 4096 + row * 256 + seg * 8);
                *(bf16x8*)(xT + ((row * 512 + seg * 16) ^ ((row & 7) << 4))) = v;
            }
            __syncthreads();
            // gx: waves 0-5 (gate, K-half), 8 MFMA each, B-frags from wB
            if (w < 6) {
                f32x4 xH = {}, xL = {};
                int brow = gg * 16 + lr;
                int bsw = (brow & 7) << 4;
                int bb = brow * 512 + (lane >> 4) * 16;
#pragma unroll
                for (int k0 = 0; k0 < 4; ++k0) {
                    int kk = kh * 4 + k0;
                    bf16x8 a = *(const bf16x8*)(xT +
                        ((lr * 512 + (lane >> 4) * 16 + kk * 64) ^ ((lr & 7) << 4)));
                    bf16x8 bh = *(const bf16x8*)(wB + ((bb + kk * 64) ^ bsw));
                    bf16x8 bl = *(const bf16x8*)(wB + 24576 + ((bb + kk * 64) ^ bsw));
                    xH = MFMA(a, bh, xH);
                    xL = MFMA(a, bl, xL);
                }
                f32x4 acc = xH + xL;
                float* dst = exX + (gg * 2 + kh) * 256;
#pragma unroll
                for (int r = 0; r < 4; ++r)
                    dst[((lane >> 4) * 4 + r) * 16 + lr] = acc[r];
            }
            __syncthreads();
            // elementwise GRU update for cohort c (256 threads), h -> pk
            if (ecoh == c) {
                int i = er * 16 + eunit;
                float ghr = exG[((c * 3 + 0) * 2) * 256 + i] +
                            exG[((c * 3 + 0) * 2 + 1) * 256 + i];
                float ghz = exG[((c * 3 + 1) * 2) * 256 + i] +
                            exG[((c * 3 + 1) * 2 + 1) * 256 + i];
                float ghn = exG[((c * 3 + 2) * 2) * 256 + i] +
                            exG[((c * 3 + 2) * 2 + 1) * 256 + i];
                float gxr = exX[0 * 256 + i] + exX[1 * 256 + i];
                float gxz = exX[2 * 256 + i] + exX[3 * 256 + i];
                float gxn = exX[4 * 256 + i] + exX[5 * 256 + i];
                float pr = gxr + ghr + bi0 + bh0;
                float pz = gxz + ghz + bi1 + bh1;
                float xn = gxn + bi2;
                float hn = ghn + bh2;
                float rr = 1.f / (1.f + __expf(-pr));
                float zz = 1.f / (1.f + __expf(-pz));
                float e2 = __expf(2.f * (xn + rr * hn));
                float nn = 1.f - 2.f / (e2 + 1.f);
                hreg = (1.f - zz) * nn + zz * hreg;
                *(__bf16*)(pk + i * 2) = (__bf16)hreg;
                if (t == Tn - 1)
                    out[(size_t)(g * 32 + erow) * 512 + l * 16 + eunit] = hreg;
            }
            __syncthreads();
            // wave 0: packed 16B h stores, wave-local drain, post h flag
            if (w == 0) {
                if (lane < 32) {
                    f32x4 pv = *(const f32x4*)(pk + lane * 16);
                    st16_mall(hb_g + hcur * HBP + (c * 16 + (lane >> 1)) * 512 +
                              l * 16 + (lane & 1) * 8, pv);
                }
                VDRAIN();
                if (lane == 0) ast32(fl + 64 + c * 32 + l, tg);
            }
            // next slot's poll-sync orders pk/xT reuse
        }
    }
}

// ---------------- host launcher ----------------

extern "C" void kernel_launch(void* const* d_in, const int* in_sizes, int n_in,
                              void* d_out, int out_size, void* d_ws, size_t ws_size,
                              hipStream_t stream) {
    const float* x_l = (const float*)d_in[0];
    const float* x_e = (const float*)d_in[1];
    const float* Wh  = (const float*)d_in[2];
    const float* Wx  = (const float*)d_in[3];
    const float* bt  = (const float*)d_in[4];
    const float* Wih = (const float*)d_in[5];
    const float* Whh = (const float*)d_in[6];
    const float* bih = (const float*)d_in[7];
    const float* bhh = (const float*)d_in[8];

    char* ws = (char*)d_ws;
    __bf16* WhT_hi = (__bf16*)(ws + 0);          //  262144
    __bf16* WhT_lo = (__bf16*)(ws + 262144);     //  262144
    __bf16* WxTP   = (__bf16*)(ws + 524288);     //   16384
    __bf16* Wih_hi = (__bf16*)(ws + 540672);     //  786432
    __bf16* Wih_lo = (__bf16*)(ws + 1327104);    //  786432
    __bf16* Whh_hi = (__bf16*)(ws + 2113536);    // 1572864
    __bf16* Whh_lo = (__bf16*)(ws + 3686400);    // 1572864
    __bf16* XinP   = (__bf16*)(ws + 5259264);    // 5505024
    __bf16* xp     = (__bf16*)(ws + 10764288);   //  131072 [g][coh][16][256]
    __bf16* hbf    = (__bf16*)(ws + 10895360);   //  524288 [par][g][32][512]
    u32t*   cnt    = (u32t*)  (ws + 11419648);   //    4096 -> total ~11.4 MB

    pack_wh<<<512, 256, 0, stream>>>(Wh, WhT_hi, WhT_lo);
    pack_wx<<<32, 256, 0, stream>>>(Wx, WxTP);
    pack_split<<<1536, 256, 0, stream>>>(Wih, Wih_hi, Wih_lo, 1536 * 256);
    pack_split<<<3072, 256, 0, stream>>>(Whh, Whh_hi, Whh_lo, 1536 * 512);
    pack_xin<<<10752, 256, 0, stream>>>(x_l, x_e, XinP);
    hipMemsetAsync(hbf, 0, 524288, stream);
    hipMemsetAsync(cnt, 0, 4096, stream);

    gru_persist<<<256, 512, 0, stream>>>(
        WhT_hi, WhT_lo, WxTP, Wih_hi, Wih_lo, Whh_hi, Whh_lo, XinP,
        bt, bih, bhh, xp, hbf, cnt, (float*)d_out);
}

// Round 11
// 2145.728 us; speedup vs baseline: 1.0173x; 1.0173x over previous
//
#include <hip/hip_runtime.h>
#include <hip/hip_bf16.h>

// Problem constants
#define Bn 256
#define Tn 336
#define KE 16

typedef __attribute__((ext_vector_type(8))) __bf16 bf16x8;
typedef __attribute__((ext_vector_type(4))) float f32x4;
typedef unsigned long long u64t;
typedef unsigned int u32t;

#define MFMA(a, b, c) __builtin_amdgcn_mfma_f32_16x16x32_bf16((a), (b), (c), 0, 0, 0)
#define BC8(x) __builtin_bit_cast(bf16x8, (x))
#define VDRAIN() asm volatile("s_waitcnt vmcnt(0)" ::: "memory")

// ---------------- pack kernels (once per launch) ----------------

__global__ void pack_wh(const float* __restrict__ Wh, __bf16* __restrict__ hi,
                        __bf16* __restrict__ lo) {
    int i = blockIdx.x * 256 + threadIdx.x;  // 512*256
    int k = i >> 8, n = i & 255;
    float v = Wh[i];
    __bf16 h = (__bf16)v;
    hi[n * 512 + k] = h;
    lo[n * 512 + k] = (__bf16)(v - (float)h);
}

__global__ void pack_wx(const float* __restrict__ Wx, __bf16* __restrict__ out) {
    int i = blockIdx.x * 256 + threadIdx.x;  // 256*32
    int n = i >> 5, k = i & 31;
    out[i] = (__bf16)((k < 17) ? Wx[k * 256 + n] : 0.f);
}

__global__ void pack_split(const float* __restrict__ in, __bf16* __restrict__ hi,
                           __bf16* __restrict__ lo, int n) {
    int i = blockIdx.x * 256 + threadIdx.x;
    if (i >= n) return;
    float v = in[i];
    __bf16 h = (__bf16)v;
    hi[i] = h;
    lo[i] = (__bf16)(v - (float)h);
}

__global__ void pack_xin(const float* __restrict__ xl, const float* __restrict__ xe,
                         __bf16* __restrict__ out) {
    int i = blockIdx.x * 256 + threadIdx.x;  // 336*256*32
    int k = i & 31, b = (i >> 5) & 255, t = i >> 13;
    float v = 0.f;
    if (k == 0) v = xl[b * Tn + t];
    else if (k < 17) v = xe[(b * Tn + t) * KE + (k - 1)];
    out[i] = (__bf16)v;
}

// ---------------- MALL-coherent helpers (relaxed agent = sc1) ----------------

__device__ __forceinline__ u32t ald32(const u32t* p) {
    return __hip_atomic_load(p, __ATOMIC_RELAXED, __HIP_MEMORY_SCOPE_AGENT);
}
__device__ __forceinline__ void ast32(u32t* p, u32t v) {
    __hip_atomic_store(p, v, __ATOMIC_RELAXED, __HIP_MEMORY_SCOPE_AGENT);
}
__device__ __forceinline__ bf16x8 ld16_mall(const __bf16* p) {
    union { u64t q[2]; bf16x8 v; } r;
    const u64t* q = (const u64t*)p;
    r.q[0] = __hip_atomic_load(q, __ATOMIC_RELAXED, __HIP_MEMORY_SCOPE_AGENT);
    r.q[1] = __hip_atomic_load(q + 1, __ATOMIC_RELAXED, __HIP_MEMORY_SCOPE_AGENT);
    return r.v;
}
__device__ __forceinline__ void st16_mall(__bf16* p, f32x4 v) {
    union { f32x4 f; u64t q[2]; } u; u.f = v;
    __hip_atomic_store((u64t*)p, u.q[0], __ATOMIC_RELAXED, __HIP_MEMORY_SCOPE_AGENT);
    __hip_atomic_store((u64t*)p + 1, u.q[1], __ATOMIC_RELAXED, __HIP_MEMORY_SCOPE_AGENT);
}

// ---------------- persistent GRU kernel ----------------
// grid = 256 blocks (1/CU), block = 512 threads (8 waves). group g = bid&7
// (32 blocks, batch rows [g*32,+32)); block l = bid>>3 owns units [16l,+16).
// Waves 0..5: gh (gate=w>>1, row-half=w&1), full K=512, W_hh hi/lo pinned.
// Wave 6: 16x16 x' tile (rows (l&1)*16.., cols (l>>1)*16..), Wh pinned;
//         packs tile -> 32x16B MALL stores -> wave-local drain -> posts flag.
// Wave 7: polls h-flags at step start, polls x'-flags during phase A
//         (overlapped with gh compute), stores packed h at step end.

__global__ __launch_bounds__(512, 2)
__attribute__((amdgpu_waves_per_eu(2, 2)))
void gru_persist(
    const __bf16* __restrict__ WhT_hi, const __bf16* __restrict__ WhT_lo,
    const __bf16* __restrict__ WxTP,
    const __bf16* __restrict__ Wih_hi, const __bf16* __restrict__ Wih_lo,
    const __bf16* __restrict__ Whh_hi, const __bf16* __restrict__ Whh_lo,
    const __bf16* __restrict__ XinP,
    const float* __restrict__ b_t, const float* __restrict__ b_ih,
    const float* __restrict__ b_hh,
    __bf16* xp, __bf16* hbf,  // MALL-shared (sc1)
    u32t* cnt, float* __restrict__ out)
{
    __shared__ __align__(16) char lds[108032];
    // [0,32768):        hT   32 rows x 1024B (bf16 k=512), XOR-swizzled
    // [32768,49152):    xT   32 rows x 512B  (bf16 k=256), XOR-swizzled
    // [49152,57344):    ex   [2 half][4 plane][16 row][16 unit] f32
    // [57344,57856):    pkX  512B  (wave6 x' tile pack)
    // [57856,58880):    pkH  1024B (h tile pack)
    // [58880,108032):   wB   W_ih slice: hi 48x512B | lo 48x512B, swizzled

    char* hT = lds;
    char* xT = lds + 32768;
    float* ex = (float*)(lds + 49152);
    char* pkX = lds + 57344;
    char* pkH = lds + 57856;
    char* wB = lds + 58880;

    const int bid = blockIdx.x;
    const int g = bid & 7, l = bid >> 3;
    const int tid = threadIdx.x;
    const int w = tid >> 6, lane = tid & 63;
    const int lr = lane & 15, ko = (lane >> 4) << 3;

    __bf16* hb_g = hbf + g * (32 * 512);
    __bf16* xp_g = xp + g * (32 * 256);
    u32t* fl = cnt + g * 128;  // [0,32)=x'-flags, [64,96)=h-flags (2 lines)

    const int mw = (w == 6) ? (l & 1) : (w & 1);  // row-half for this wave
    const int gg = (w < 6) ? (w >> 1) : 0;        // gate (waves 0..5)
    const int cb = l >> 1;                        // wave6 col-block

    // ---- stage W_ih slice -> wB LDS (once; reused 336 steps) ----
#pragma unroll
    for (int e = 0; e < 3; ++e) {
        int idx = e * 512 + tid;            // 1536 chunks: 48 rows x 32 segs
        int row = idx >> 5, seg = idx & 31;
        int gate = row >> 4, r = row & 15;
        size_t src = (size_t)(gate * 512 + l * 16 + r) * 256 + seg * 8;
        int dst = (row * 512 + seg * 16) ^ ((row & 7) << 4);
        *(bf16x8*)(wB + dst)         = *(const bf16x8*)(Wih_hi + src);
        *(bf16x8*)(wB + 24576 + dst) = *(const bf16x8*)(Wih_lo + src);
    }

    // ---- load phase-A weights once; pinned in-loop below ----
    const __bf16 *srcH, *srcL;
    if (w < 6) {
        size_t j = (size_t)(gg * 512 + l * 16 + lr) * 512 + ko;
        srcH = Whh_hi + j; srcL = Whh_lo + j;
    } else if (w == 6) {
        size_t j = (size_t)(cb * 16 + lr) * 512 + ko;
        srcH = WhT_hi + j; srcL = WhT_lo + j;
    } else {
        srcH = Whh_hi + ko; srcL = Whh_lo + ko;  // dummy (valid) for wave 7
    }
    f32x4 wHi[16], wLo[16];
#pragma unroll
    for (int k0 = 0; k0 < 16; ++k0) {
        wHi[k0] = *(const f32x4*)(srcH + k0 * 32);
        wLo[k0] = *(const f32x4*)(srcL + k0 * 32);
    }
    bf16x8 wxf = {};
    float bt_r = 0.f;
    if (w == 6) {
        wxf = *(const bf16x8*)(WxTP + (size_t)(cb * 16 + lr) * 32 + ko);
        bt_r = b_t[cb * 16 + lr];
    }

    // elementwise per-thread state: (row = tid>>4, unit = tid&15)
    const int erow = tid >> 4, eunit = tid & 15;
    float bi0, bi1, bi2, bh0, bh1, bh2;
    {
        int u = l * 16 + eunit;
        bi0 = b_ih[u]; bi1 = b_ih[512 + u]; bi2 = b_ih[1024 + u];
        bh0 = b_hh[u]; bh1 = b_hh[512 + u]; bh2 = b_hh[1024 + u];
    }
    float hreg = 0.f;  // fp32 h carried in-register across all steps
    const int exi = (erow >> 4) * 1024 + (erow & 15) * 16 + eunit;

    // MFMA fragment LDS addressing
    const int arow = mw * 16 + lr;
    const int swz = (arow & 7) << 4;
    const int abaseH = arow * 1024 + (lane >> 4) * 16;
    const int abaseX = arow * 512 + (lane >> 4) * 16;
    const int brow = gg * 16 + lr;
    const int bswz = (brow & 7) << 4;
    const int bbase = brow * 512 + (lane >> 4) * 16;

    __syncthreads();  // wB staged before any use

    for (int t = 0; t < Tn; ++t) {
        const u32t tg = (u32t)(t + 1);

        // pin phase-A weights as loop-carried opaque register values
#pragma unroll
        for (int k0 = 0; k0 < 16; ++k0)
            asm volatile("" : "+v"(wHi[k0]), "+v"(wLo[k0]));

        // wave 6: issue xin load EARLY (hides L3 latency under staging+gh)
        bf16x8 ax = {};
        if (w == 6)
            ax = *(const bf16x8*)(XinP +
                ((size_t)t * 256 + g * 32 + mw * 16 + lr) * 32 + ko);

        // ---- wave 7: poll h[t-1] flags (t=0 passes on memset zeros) ----
        if (w == 7) {
            const u32t* fp = fl + 64 + (lane & 31);
            for (;;) {
                u32t v = ald32(fp);
                if (__all((int)(v >= (u32t)t))) break;
                __builtin_amdgcn_s_sleep(1);
            }
        }
        __syncthreads();

        // ---- stage h[t-1] -> hT (2048 x 16B chunks, 4/thread) ----
#pragma unroll
        for (int e = 0; e < 4; ++e) {
            int idx = e * 512 + tid;
            int row = idx >> 6, seg = idx & 63;
            bf16x8 v = ld16_mall(hb_g + row * 512 + seg * 8);
            *(bf16x8*)(hT + ((row * 1024 + seg * 16) ^ ((row & 7) << 4))) = v;
        }
        __syncthreads();

        // ---- phase A: gh (waves 0-5) / x' (wave 6) / x'-flag poll (wave 7)
        f32x4 accG = {};
        if (w < 6) {
            f32x4 aH = {}, aL = {};
#pragma unroll
            for (int k0 = 0; k0 < 16; ++k0) {
                bf16x8 a = *(const bf16x8*)(hT + ((abaseH + k0 * 64) ^ swz));
                aH = MFMA(a, BC8(wHi[k0]), aH);
                aL = MFMA(a, BC8(wLo[k0]), aL);
            }
            accG = aH + aL;  // kept in registers through phase B
        } else if (w == 6) {
            f32x4 aH = {}, aL = {};
#pragma unroll
            for (int k0 = 0; k0 < 16; ++k0) {
                bf16x8 a = *(const bf16x8*)(hT + ((abaseH + k0 * 64) ^ swz));
                aH = MFMA(a, BC8(wHi[k0]), aH);
                aL = MFMA(a, BC8(wLo[k0]), aL);
            }
            aH = MFMA(ax, wxf, aH);
            f32x4 acc = aH + aL;
            // tanh -> pack tile in pkX
#pragma unroll
            for (int r = 0; r < 4; ++r) {
                int row = (lane >> 4) * 4 + r;
                float e2 = __expf(2.f * (acc[r] + bt_r));
                float tv = 1.f - 2.f / (e2 + 1.f);
                *(__bf16*)(pkX + (row * 16 + lr) * 2) = (__bf16)tv;
            }
            // 32 x 16B chunk stores, wave-local drain, post x' flag
            if (lane < 32) {
                f32x4 pv = *(const f32x4*)(pkX + lane * 16);
                st16_mall(xp_g + (mw * 16 + (lane >> 1)) * 256 + cb * 16 +
                          (lane & 1) * 8, pv);
            }
            VDRAIN();
            if (lane == 0) ast32(fl + l, tg);
        } else {
            // wave 7: poll all 32 x'-flags (overlaps gh compute)
            const u32t* fp = fl + (lane & 31);
            for (;;) {
                u32t v = ald32(fp);
                if (__all((int)(v >= tg))) break;
                __builtin_amdgcn_s_sleep(1);
            }
        }
        __syncthreads();

        // ---- stage x'[t] -> xT (1024 x 16B chunks, 2/thread) ----
#pragma unroll
        for (int e = 0; e < 2; ++e) {
            int idx = e * 512 + tid;
            int row = idx >> 5, seg = idx & 31;
            bf16x8 v = ld16_mall(xp_g + row * 256 + seg * 8);
            *(bf16x8*)(xT + ((row * 512 + seg * 16) ^ ((row & 7) << 4))) = v;
        }
        __syncthreads();

        // ---- phase B: gx = x' @ W_ih.T (waves 0-5), K=256 hi/lo ----
        if (w < 6) {
            f32x4 xH = {}, xL = {};
#pragma unroll
            for (int k0 = 0; k0 < 8; ++k0) {
                bf16x8 a  = *(const bf16x8*)(xT + ((abaseX + k0 * 64) ^ swz));
                bf16x8 bh = *(const bf16x8*)(wB + ((bbase + k0 * 64) ^ bswz));
                bf16x8 bl = *(const bf16x8*)(wB + 24576 +
                                             ((bbase + k0 * 64) ^ bswz));
                xH = MFMA(a, bh, xH);
                xL = MFMA(a, bl, xL);
            }
            f32x4 accX = xH + xL;
            float* exm = ex + mw * 1024;
            if (gg < 2) {
#pragma unroll
                for (int r = 0; r < 4; ++r)
                    exm[gg * 256 + ((lane >> 4) * 4 + r) * 16 + lr] =
                        accG[r] + accX[r];
            } else {
#pragma unroll
                for (int r = 0; r < 4; ++r) {
                    exm[2 * 256 + ((lane >> 4) * 4 + r) * 16 + lr] = accX[r];
                    exm[3 * 256 + ((lane >> 4) * 4 + r) * 16 + lr] = accG[r];
                }
            }
        }
        __syncthreads();

        // ---- elementwise GRU update (all 512 threads, 1 elem each) ----
        {
            float pr = ex[exi]       + bi0 + bh0;
            float pz = ex[exi + 256] + bi1 + bh1;
            float xn = ex[exi + 512] + bi2;
            float hn = ex[exi + 768] + bh2;
            float rr = 1.f / (1.f + __expf(-pr));
            float zz = 1.f / (1.f + __expf(-pz));
            float e2 = __expf(2.f * (xn + rr * hn));
            float nn = 1.f - 2.f / (e2 + 1.f);
            hreg = (1.f - zz) * nn + zz * hreg;
            *(__bf16*)(pkH + (erow * 16 + eunit) * 2) = (__bf16)hreg;
            if (t == Tn - 1)
                out[(size_t)(g * 32 + erow) * 512 + l * 16 + eunit] = hreg;
        }
        __syncthreads();

        // ---- wave 7: packed h stores (64 x 16B), drain, post h flag ----
        if (w == 7) {
            f32x4 pv = *(const f32x4*)(pkH + lane * 16);
            st16_mall(hb_g + (lane >> 1) * 512 + l * 16 + (lane & 1) * 8, pv);
            VDRAIN();
            if (lane == 0) ast32(fl + 64 + l, tg);
        }
        // no trailing block sync: next step's h-poll + sync orders reuse
    }
}

// ---------------- host launcher ----------------

extern "C" void kernel_launch(void* const* d_in, const int* in_sizes, int n_in,
                              void* d_out, int out_size, void* d_ws, size_t ws_size,
                              hipStream_t stream) {
    const float* x_l = (const float*)d_in[0];
    const float* x_e = (const float*)d_in[1];
    const float* Wh  = (const float*)d_in[2];
    const float* Wx  = (const float*)d_in[3];
    const float* bt  = (const float*)d_in[4];
    const float* Wih = (const float*)d_in[5];
    const float* Whh = (const float*)d_in[6];
    const float* bih = (const float*)d_in[7];
    const float* bhh = (const float*)d_in[8];

    char* ws = (char*)d_ws;
    __bf16* WhT_hi = (__bf16*)(ws + 0);          //  262144
    __bf16* WhT_lo = (__bf16*)(ws + 262144);     //  262144
    __bf16* WxTP   = (__bf16*)(ws + 524288);     //   16384
    __bf16* Wih_hi = (__bf16*)(ws + 540672);     //  786432
    __bf16* Wih_lo = (__bf16*)(ws + 1327104);    //  786432
    __bf16* Whh_hi = (__bf16*)(ws + 2113536);    // 1572864
    __bf16* Whh_lo = (__bf16*)(ws + 3686400);    // 1572864
    __bf16* XinP   = (__bf16*)(ws + 5259264);    // 5505024
    __bf16* xp     = (__bf16*)(ws + 10764288);   //  131072
    __bf16* hbf    = (__bf16*)(ws + 10895360);   //  262144
    u32t*   cnt    = (u32t*)  (ws + 11157504);   //    4096 -> total ~11.2 MB

    pack_wh<<<512, 256, 0, stream>>>(Wh, WhT_hi, WhT_lo);
    pack_wx<<<32, 256, 0, stream>>>(Wx, WxTP);
    pack_split<<<1536, 256, 0, stream>>>(Wih, Wih_hi, Wih_lo, 1536 * 256);
    pack_split<<<3072, 256, 0, stream>>>(Whh, Whh_hi, Whh_lo, 1536 * 512);
    pack_xin<<<10752, 256, 0, stream>>>(x_l, x_e, XinP);
    hipMemsetAsync(hbf, 0, 262144, stream);
    hipMemsetAsync(cnt, 0, 4096, stream);

    gru_persist<<<256, 512, 0, stream>>>(
        WhT_hi, WhT_lo, WxTP, Wih_hi, Wih_lo, Whh_hi, Whh_lo, XinP,
        bt, bih, bhh, xp, hbf, cnt, (float*)d_out);
}